// Round 6
// baseline (748.460 us; speedup 1.0000x reference)
//
#include <hip/hip_runtime.h>
#include <hip/hip_bf16.h>

typedef unsigned short u16;
typedef __bf16 bfv8 __attribute__((ext_vector_type(8)));
typedef float f32x4 __attribute__((ext_vector_type(4)));
typedef unsigned int u32x2 __attribute__((ext_vector_type(2)));
typedef unsigned int u32x4 __attribute__((ext_vector_type(4)));

#define HH 512
#define BERT_D 768

__device__ __forceinline__ float gelu_f(float x) {
  return 0.5f * x * (1.0f + erff(x * 0.70710678118654752440f));
}
__device__ __forceinline__ float us2f(u16 u) {
  union { unsigned int i; float f; } c; c.i = ((unsigned int)u) << 16; return c.f;
}
__device__ __forceinline__ u16 f2us(float f) {
  union { float f; unsigned int i; } c; c.f = f;
  unsigned int i = c.i;
  i += 0x7FFFu + ((i >> 16) & 1u);
  return (u16)(i >> 16);
}
__device__ __forceinline__ void gl_lds16(const u16* g, u16* l) {
  __builtin_amdgcn_global_load_lds((const __attribute__((address_space(1))) void*)g,
                                   (__attribute__((address_space(3))) void*)l, 16, 0, 0);
}

// ---------------- conversion kernels ----------------
__global__ void k_convert_x(const float* __restrict__ x, u16* __restrict__ semb,
                            int* __restrict__ idx, int Nn) {
  const int n = blockIdx.x;
  const int t = threadIdx.x;
  const float* xr = x + (size_t)n * (BERT_D + 1);
  u16* sr = semb + (size_t)n * BERT_D;
#pragma unroll
  for (int i = 0; i < 3; ++i) sr[t + i * 256] = f2us(xr[t + i * 256]);
  if (t == 0) idx[n] = (int)xr[BERT_D];
}

__global__ void k_transpose_bf16(const float* __restrict__ src, u16* __restrict__ dst,
                                 int K, int Nn) {
  int i = blockIdx.x * blockDim.x + threadIdx.x;
  if (i >= K * Nn) return;
  int k = i / Nn, j = i - k * Nn;
  dst[(size_t)j * K + k] = f2us(src[i]);
}

// ---------------- graph prep ----------------
__global__ void k_deg(const int* __restrict__ dst, int* __restrict__ deg, int E) {
  int e = blockIdx.x * blockDim.x + threadIdx.x;
  if (e < E) atomicAdd(&deg[dst[e]], 1);
}

__launch_bounds__(256)
__global__ void k_part(const int* __restrict__ deg, int* __restrict__ part, int Nn) {
  const int i = blockIdx.x * 256 + threadIdx.x;
  int v = (i < Nn) ? deg[i] : 0;
#pragma unroll
  for (int o = 32; o; o >>= 1) v += __shfl_xor(v, o);
  __shared__ int ws4[4];
  if ((threadIdx.x & 63) == 0) ws4[threadIdx.x >> 6] = v;
  __syncthreads();
  if (threadIdx.x == 0) part[blockIdx.x] = ws4[0] + ws4[1] + ws4[2] + ws4[3];
}

__launch_bounds__(256)
__global__ void k_scan_part(int* __restrict__ part, int* __restrict__ row_ptr,
                            int nb, int Nn) {
  __shared__ int sm[256];
  const int t = threadIdx.x;
  int v = (t < nb) ? part[t] : 0;
  sm[t] = v;
  __syncthreads();
  for (int d = 1; d < 256; d <<= 1) {
    int u = (t >= d) ? sm[t - d] : 0;
    __syncthreads();
    sm[t] += u;
    __syncthreads();
  }
  if (t < nb) part[t] = sm[t] - v;
  if (t == 255) row_ptr[Nn] = sm[255];
}

__launch_bounds__(256)
__global__ void k_scan_write(const int* __restrict__ deg, const int* __restrict__ part,
                             int* __restrict__ row_ptr, int* __restrict__ cursor,
                             float* __restrict__ dinv, int Nn) {
  __shared__ int sm[256];
  const int t = threadIdx.x;
  const int i = blockIdx.x * 256 + t;
  int v = (i < Nn) ? deg[i] : 0;
  sm[t] = v;
  __syncthreads();
  for (int d = 1; d < 256; d <<= 1) {
    int u = (t >= d) ? sm[t - d] : 0;
    __syncthreads();
    sm[t] += u;
    __syncthreads();
  }
  if (i < Nn) {
    int pre = part[blockIdx.x] + sm[t] - v;
    row_ptr[i] = pre;
    cursor[i] = pre;
    dinv[i] = rsqrtf((float)v + 1.0f);
  }
}

__global__ void k_csr(const int* __restrict__ src, const int* __restrict__ dst,
                      int* __restrict__ cursor, int* __restrict__ csr_src, int E) {
  int e = blockIdx.x * blockDim.x + threadIdx.x;
  if (e >= E) return;
  int d = dst[e];
  int pos = atomicAdd(&cursor[d], 1);
  csr_src[pos] = src[e];
}

// ---------------- GEMM: C[M][512] = A[M][Kd] * B^T, 128x256 tile ----------------
// 1-D grid (Mtiles*2); bijective chunked XCD swizzle keeps both column-tiles of
// an A-panel on the same XCD so the second one hits L2.
// EPI=0: plain   EPI=1: +bias +slice_emb[idx]   EPI=2: row-scale by dscale[row]
template <int EPI>
__launch_bounds__(256, 2)
__global__ void k_gemm_bt(const u16* __restrict__ A, int lda,
                          const u16* __restrict__ B, int ldb,
                          u16* __restrict__ C, int M, int Kd,
                          const float* __restrict__ bias,
                          const float* __restrict__ emb,
                          const int* __restrict__ idx,
                          const float* __restrict__ dscale) {
  __shared__ alignas(16) u16 As[128 * 64];
  __shared__ alignas(16) u16 Bs[256 * 64];
  const int t = threadIdx.x;
  const int l = t & 63;
  const int w = t >> 6;
  const int wro = (w >> 1) * 64;
  const int wco = (w & 1) * 128;
  const int lr = l & 15;
  const int kg = (l >> 4) * 8;
  // bijective chunked XCD transform (m204): dispatch id -> contiguous per-XCD range
  const int nwg = gridDim.x;
  const int id = blockIdx.x;
  const int q8 = nwg >> 3, r8 = nwg & 7;
  const int xcd = id & 7, rk = id >> 3;
  const int swz = (xcd < r8 ? xcd * (q8 + 1) : r8 * (q8 + 1) + (xcd - r8) * q8) + rk;
  const int brow = (swz >> 1) * 128;
  const int bcol = (swz & 1) * 256;

  f32x4 acc[4][8] = {};

  for (int k0 = 0; k0 < Kd; k0 += 64) {
#pragma unroll
    for (int i = 0; i < 4; ++i) {
      const int eo = (i * 256 + t) * 8;
      const int r = eo >> 6;
      const int c = eo & 63;
      int gr = brow + r;
      if (gr > M - 1) gr = M - 1;
      gl_lds16(A + (size_t)gr * lda + (k0 + c), As + eo);
    }
#pragma unroll
    for (int i = 0; i < 8; ++i) {
      const int eo = (i * 256 + t) * 8;
      const int r = eo >> 6;
      const int c = eo & 63;
      gl_lds16(B + (size_t)(bcol + r) * ldb + (k0 + c), Bs + eo);
    }
    __syncthreads();
#pragma unroll
    for (int ks = 0; ks < 2; ++ks) {
      bfv8 af[4], bfr[8];
#pragma unroll
      for (int m = 0; m < 4; ++m)
        af[m] = __builtin_bit_cast(bfv8, *(const uint4*)(As + (wro + m * 16 + lr) * 64 + ks * 32 + kg));
#pragma unroll
      for (int n = 0; n < 8; ++n)
        bfr[n] = __builtin_bit_cast(bfv8, *(const uint4*)(Bs + (wco + n * 16 + lr) * 64 + ks * 32 + kg));
#pragma unroll
      for (int m = 0; m < 4; ++m)
#pragma unroll
        for (int n = 0; n < 8; ++n)
          acc[m][n] = __builtin_amdgcn_mfma_f32_16x16x32_bf16(af[m], bfr[n], acc[m][n], 0, 0, 0);
    }
    __syncthreads();
  }

#pragma unroll
  for (int m = 0; m < 4; ++m) {
#pragma unroll
    for (int r = 0; r < 4; ++r) {
      const int row = brow + wro + m * 16 + (l >> 4) * 4 + r;
      if (row >= M) continue;
      const float sc = (EPI == 2) ? dscale[row] : 1.0f;
#pragma unroll
      for (int n = 0; n < 8; ++n) {
        const int col = bcol + wco + n * 16 + lr;
        float v = acc[m][n][r];
        if (EPI == 1) v += bias[col] + emb[idx[row] * HH + col];
        if (EPI == 2) v *= sc;
        C[(size_t)row * HH + col] = f2us(v);
      }
    }
  }
}

// ---------------- LayerNorm + GELU (one wave per row) ----------------
__launch_bounds__(256)
__global__ void k_ln_gelu(const u16* __restrict__ h0, const float* __restrict__ gw,
                          const float* __restrict__ bw, u16* __restrict__ hout, int Nn) {
  const int wid = (int)((blockIdx.x * (long long)blockDim.x + threadIdx.x) >> 6);
  if (wid >= Nn) return;
  const int l = threadIdx.x & 63;
  uint4 q = *(const uint4*)(h0 + (size_t)wid * HH + l * 8);
  const u16* us = (const u16*)&q;
  float f[8]; float s = 0.f, s2 = 0.f;
#pragma unroll
  for (int j = 0; j < 8; ++j) { f[j] = us2f(us[j]); s += f[j]; s2 += f[j] * f[j]; }
#pragma unroll
  for (int o = 32; o; o >>= 1) { s += __shfl_xor(s, o); s2 += __shfl_xor(s2, o); }
  const float mean = s * (1.f / 512.f);
  const float var = s2 * (1.f / 512.f) - mean * mean;
  const float rs = rsqrtf(var + 1e-5f);
  union { u16 ov[8]; uint4 q; } o;
#pragma unroll
  for (int j = 0; j < 8; ++j) {
    int col = l * 8 + j;
    float y = (f[j] - mean) * rs * gw[col] + bw[col];
    o.ov[j] = f2us(gelu_f(y));
  }
  *(uint4*)(hout + (size_t)wid * HH + l * 8) = o.q;
}

// ---------------- GCN aggregate (one wave per node, rows pre-scaled by dinv[src]) ----
// hwS[u] = (h @ W) * dinv[u].  out = gelu((self + sum) * dv + b).  8-deep MLP unroll.
__launch_bounds__(256)
__global__ void k_agg(const u16* __restrict__ hwS, const int* __restrict__ row_ptr,
                      const int* __restrict__ csr_src, const float* __restrict__ dinv,
                      const float* __restrict__ bias, u16* __restrict__ hout, int Nn) {
  const int wid = (int)((blockIdx.x * (long long)blockDim.x + threadIdx.x) >> 6);
  if (wid >= Nn) return;
  const int l = threadIdx.x & 63;
  const int cb = l * 8;
  const int lo = row_ptr[wid], hi = row_ptr[wid + 1];
  const float dv = dinv[wid];
  float acc[8];
  {  // self row (hoisted: overlaps with first gathers)
    uint4 q = *(const uint4*)(hwS + (size_t)wid * HH + cb);
    const u16* p = (const u16*)&q;
#pragma unroll
    for (int j = 0; j < 8; ++j) acc[j] = us2f(p[j]);
  }
  int e = lo;
  for (; e + 8 <= hi; e += 8) {
    int u[8];
    uint4 q[8];
#pragma unroll
    for (int k = 0; k < 8; ++k) u[k] = csr_src[e + k];
#pragma unroll
    for (int k = 0; k < 8; ++k) q[k] = *(const uint4*)(hwS + (size_t)u[k] * HH + cb);
#pragma unroll
    for (int k = 0; k < 8; ++k) {
      const u16* p = (const u16*)&q[k];
#pragma unroll
      for (int j = 0; j < 8; ++j) acc[j] += us2f(p[j]);
    }
  }
  for (; e + 4 <= hi; e += 4) {
    int u[4];
    uint4 q[4];
#pragma unroll
    for (int k = 0; k < 4; ++k) u[k] = csr_src[e + k];
#pragma unroll
    for (int k = 0; k < 4; ++k) q[k] = *(const uint4*)(hwS + (size_t)u[k] * HH + cb);
#pragma unroll
    for (int k = 0; k < 4; ++k) {
      const u16* p = (const u16*)&q[k];
#pragma unroll
      for (int j = 0; j < 8; ++j) acc[j] += us2f(p[j]);
    }
  }
  for (; e < hi; ++e) {
    const int u = csr_src[e];
    uint4 q = *(const uint4*)(hwS + (size_t)u * HH + cb);
    const u16* p = (const u16*)&q;
#pragma unroll
    for (int j = 0; j < 8; ++j) acc[j] += us2f(p[j]);
  }
  union { u16 ov[8]; u32x4 q; } o;
#pragma unroll
  for (int j = 0; j < 8; ++j) {
    float v = acc[j] * dv + bias[cb + j];
    o.ov[j] = f2us(gelu_f(v));
  }
  __builtin_nontemporal_store(o.q, (u32x4*)(hout + (size_t)wid * HH + cb));
}

// ---------------- pooling: (G x RS) blocks, NT vector loads, atomic partials ----
#define POOL_RS 16
__launch_bounds__(256)
__global__ void k_pool2(const u16* __restrict__ h1, const u16* __restrict__ h2,
                        const int* __restrict__ batch, float* __restrict__ hg, int Nn) {
  const int g = blockIdx.x;
  const int chunk = blockIdx.y;
  const int t = threadIdx.x;
  const int w = t >> 6;
  const int l = t & 63;
  const int cb = l * 8;
  int lo, hi;
  { int a = 0, b = Nn; while (a < b) { int m = (a + b) >> 1; if (batch[m] < g) a = m + 1; else b = m; } lo = a; }
  { int a = 0, b = Nn; while (a < b) { int m = (a + b) >> 1; if (batch[m] < g + 1) a = m + 1; else b = m; } hi = a; }
  const int len = hi - lo;
  const int per = (len + POOL_RS - 1) / POOL_RS;
  const int rlo = lo + chunk * per;
  const int rhi = min(rlo + per, hi);
  float acc[8] = {};
  for (int r = rlo + w; r < rhi; r += 4) {
    u32x4 a = __builtin_nontemporal_load((const u32x4*)(h1 + (size_t)r * HH + cb));
    u32x4 b = __builtin_nontemporal_load((const u32x4*)(h2 + (size_t)r * HH + cb));
    const u16* ua = (const u16*)&a;
    const u16* ub = (const u16*)&b;
#pragma unroll
    for (int j = 0; j < 8; ++j) acc[j] += us2f(ua[j]) + us2f(ub[j]);
  }
  __shared__ float red[4][HH];
#pragma unroll
  for (int j = 0; j < 8; ++j) red[w][cb + j] = acc[j];
  __syncthreads();
  if (w == 0) {
#pragma unroll
    for (int j = 0; j < 8; ++j) {
      const int col = cb + j;
      float s = red[0][col] + red[1][col] + red[2][col] + red[3][col];
      if (s != 0.f) atomicAdd(&hg[(size_t)g * HH + col], s);
    }
  }
}

// ---------------- classifier (one block per group; divides by count) ---------
__launch_bounds__(256)
__global__ void k_cls(const float* __restrict__ hg, const int* __restrict__ batch,
                      const float* __restrict__ W1, const float* __restrict__ b1,
                      const float* __restrict__ W2, const float* __restrict__ b2,
                      float* __restrict__ out, int Nn) {
  const int g = blockIdx.x;
  const int t = threadIdx.x;
  __shared__ float hl[512];
  __shared__ float zl[512];
  __shared__ float pr[512];
  int lo, hi;
  { int a = 0, b = Nn; while (a < b) { int m = (a + b) >> 1; if (batch[m] < g) a = m + 1; else b = m; } lo = a; }
  { int a = 0, b = Nn; while (a < b) { int m = (a + b) >> 1; if (batch[m] < g + 1) a = m + 1; else b = m; } hi = a; }
  const float inv = 1.0f / fmaxf((float)(hi - lo), 1.0f);
  hl[t] = hg[(size_t)g * HH + t] * inv;
  hl[t + 256] = hg[(size_t)g * HH + t + 256] * inv;
  __syncthreads();
#pragma unroll
  for (int jj = 0; jj < 2; ++jj) {
    const int j = t + jj * 256;
    float a = b1[j];
    for (int k = 0; k < 512; ++k) a += hl[k] * W1[k * HH + j];
    zl[j] = gelu_f(a);
  }
  __syncthreads();
  float p0 = 0.f, p1 = 0.f;
  for (int k = t; k < 512; k += 256) { p0 += zl[k] * W2[k * 2]; p1 += zl[k] * W2[k * 2 + 1]; }
  pr[t] = p0; pr[t + 256] = p1;
  __syncthreads();
  for (int s2 = 128; s2; s2 >>= 1) {
    if (t < s2) { pr[t] += pr[t + s2]; pr[t + 256] += pr[t + 256 + s2]; }
    __syncthreads();
  }
  if (t == 0) { out[g * 2] = pr[0] + b2[0]; out[g * 2 + 1] = pr[256] + b2[1]; }
}

// ---------------- host ----------------
extern "C" void kernel_launch(void* const* d_in, const int* in_sizes, int n_in,
                              void* d_out, int out_size, void* d_ws, size_t ws_size,
                              hipStream_t stream) {
  const float* x        = (const float*)d_in[0];
  const int*   eidx     = (const int*)d_in[1];
  const int*   batch    = (const int*)d_in[2];
  const float* sem_W    = (const float*)d_in[3];
  const float* sem_b    = (const float*)d_in[4];
  const float* sl_emb   = (const float*)d_in[5];
  const float* ln_g     = (const float*)d_in[6];
  const float* ln_b     = (const float*)d_in[7];
  const float* W1       = (const float*)d_in[8];
  const float* b1       = (const float*)d_in[9];
  const float* W2       = (const float*)d_in[10];
  const float* b2       = (const float*)d_in[11];
  const float* cW1      = (const float*)d_in[12];
  const float* cb1      = (const float*)d_in[13];
  const float* cW2      = (const float*)d_in[14];
  const float* cb2      = (const float*)d_in[15];
  const int N_ = in_sizes[2];
  const int E_ = in_sizes[1] / 2;
  const int G_ = out_size / 2;
  const int* src = eidx;
  const int* dst = eidx + E_;

  char* ws = (char*)d_ws;
  size_t off = 0;
  auto alloc = [&](size_t bytes) -> void* {
    void* p = (void*)(ws + off);
    off += (bytes + 255) & ~(size_t)255;
    return p;
  };
  u16* semb = (u16*)alloc((size_t)N_ * BERT_D * sizeof(u16));
  u16* h1 = semb;                                     // reuse region A
  u16* h0 = (u16*)alloc((size_t)N_ * HH * sizeof(u16));
  u16* hw = h0;                                       // reuse region B
  u16* h = (u16*)alloc((size_t)N_ * HH * sizeof(u16));
  u16* h2 = h;                                        // reuse region C
  u16* semW_T = (u16*)alloc((size_t)HH * BERT_D * sizeof(u16));
  u16* W1T    = (u16*)alloc((size_t)HH * HH * sizeof(u16));
  u16* W2T    = (u16*)alloc((size_t)HH * HH * sizeof(u16));
  int* idx     = (int*)alloc((size_t)N_ * 4);
  int* deg     = (int*)alloc((size_t)N_ * 4);
  float* dinv  = (float*)alloc((size_t)N_ * 4);
  int* row_ptr = (int*)alloc((size_t)(N_ + 1) * 4);
  int* cursor  = (int*)alloc((size_t)N_ * 4);
  int* csr_src = (int*)alloc((size_t)E_ * 4);
  int* part    = (int*)alloc(1024);
  float* hg    = (float*)alloc((size_t)G_ * HH * 4);

  hipMemsetAsync(deg, 0, (size_t)N_ * 4, stream);
  hipMemsetAsync(hg, 0, (size_t)G_ * HH * 4, stream);

  k_convert_x<<<N_, 256, 0, stream>>>(x, semb, idx, N_);
  k_transpose_bf16<<<(BERT_D * HH + 255) / 256, 256, 0, stream>>>(sem_W, semW_T, BERT_D, HH);
  k_transpose_bf16<<<(HH * HH + 255) / 256, 256, 0, stream>>>(W1, W1T, HH, HH);
  k_transpose_bf16<<<(HH * HH + 255) / 256, 256, 0, stream>>>(W2, W2T, HH, HH);

  const int nb = (N_ + 255) / 256;
  k_deg<<<(E_ + 255) / 256, 256, 0, stream>>>(dst, deg, E_);
  k_part<<<nb, 256, 0, stream>>>(deg, part, N_);
  k_scan_part<<<1, 256, 0, stream>>>(part, row_ptr, nb, N_);
  k_scan_write<<<nb, 256, 0, stream>>>(deg, part, row_ptr, cursor, dinv, N_);
  k_csr<<<(E_ + 255) / 256, 256, 0, stream>>>(src, dst, cursor, csr_src, E_);

  const int Mtiles = (N_ + 127) / 128;
  const int wave_blocks = (N_ + 3) / 4;
  const int gemm_grid = Mtiles * 2;   // 1-D, swizzled in-kernel

  // h0 = semb @ sem_W + sem_b + slice_emb[idx]
  k_gemm_bt<1><<<gemm_grid, 256, 0, stream>>>(
      semb, BERT_D, semW_T, BERT_D, h0, N_, BERT_D, sem_b, sl_emb, idx, nullptr);
  // h = gelu(LN(h0))
  k_ln_gelu<<<wave_blocks, 256, 0, stream>>>(h0, ln_g, ln_b, h, N_);
  // conv1: hwS = (h @ W1) * dinv[row] ; h1 = gelu((self+agg)*dinv + b1)
  k_gemm_bt<2><<<gemm_grid, 256, 0, stream>>>(
      h, HH, W1T, HH, hw, N_, HH, nullptr, nullptr, nullptr, dinv);
  k_agg<<<wave_blocks, 256, 0, stream>>>(hw, row_ptr, csr_src, dinv, b1, h1, N_);
  // conv2: hwS = (h1 @ W2) * dinv[row] ; h2 = gelu((self+agg)*dinv + b2)
  k_gemm_bt<2><<<gemm_grid, 256, 0, stream>>>(
      h1, HH, W2T, HH, hw, N_, HH, nullptr, nullptr, nullptr, dinv);
  k_agg<<<wave_blocks, 256, 0, stream>>>(hw, row_ptr, csr_src, dinv, b2, h2, N_);
  // pool (h1 + h2 residual fused) + classifier
  k_pool2<<<dim3(G_, POOL_RS), 256, 0, stream>>>(h1, h2, batch, hg, N_);
  k_cls<<<G_, 256, 0, stream>>>(hg, batch, cW1, cb1, cW2, cb2, (float*)d_out, N_);
}

// Round 7
// 725.274 us; speedup vs baseline: 1.0320x; 1.0320x over previous
//
#include <hip/hip_runtime.h>
#include <hip/hip_bf16.h>

typedef unsigned short u16;
typedef __bf16 bfv8 __attribute__((ext_vector_type(8)));
typedef float f32x4 __attribute__((ext_vector_type(4)));
typedef unsigned int u32x4 __attribute__((ext_vector_type(4)));

#define HH 512
#define BERT_D 768
#define XSTRIDE 769

__device__ __forceinline__ float gelu_f(float x) {
  return 0.5f * x * (1.0f + erff(x * 0.70710678118654752440f));
}
__device__ __forceinline__ float us2f(u16 u) {
  union { unsigned int i; float f; } c; c.i = ((unsigned int)u) << 16; return c.f;
}
__device__ __forceinline__ u16 f2us(float f) {
  union { float f; unsigned int i; } c; c.f = f;
  unsigned int i = c.i;
  i += 0x7FFFu + ((i >> 16) & 1u);
  return (u16)(i >> 16);
}
__device__ __forceinline__ void gl_lds16(const u16* g, u16* l) {
  __builtin_amdgcn_global_load_lds((const __attribute__((address_space(1))) void*)g,
                                   (__attribute__((address_space(3))) void*)l, 16, 0, 0);
}

// ---------------- idx extraction ----------------
__global__ void k_idx(const float* __restrict__ x, int* __restrict__ idx, int Nn) {
  int i = blockIdx.x * blockDim.x + threadIdx.x;
  if (i < Nn) idx[i] = (int)x[(size_t)i * XSTRIDE + BERT_D];
}

__global__ void k_transpose_bf16(const float* __restrict__ src, u16* __restrict__ dst,
                                 int K, int Nn) {
  int i = blockIdx.x * blockDim.x + threadIdx.x;
  if (i >= K * Nn) return;
  int k = i / Nn, j = i - k * Nn;
  dst[(size_t)j * K + k] = f2us(src[i]);
}

// ---------------- graph prep ----------------
__global__ void k_deg(const int* __restrict__ dst, int* __restrict__ deg, int E) {
  int e = blockIdx.x * blockDim.x + threadIdx.x;
  if (e < E) atomicAdd(&deg[dst[e]], 1);
}

__launch_bounds__(256)
__global__ void k_part(const int* __restrict__ deg, int* __restrict__ part, int Nn) {
  const int i = blockIdx.x * 256 + threadIdx.x;
  int v = (i < Nn) ? deg[i] : 0;
#pragma unroll
  for (int o = 32; o; o >>= 1) v += __shfl_xor(v, o);
  __shared__ int ws4[4];
  if ((threadIdx.x & 63) == 0) ws4[threadIdx.x >> 6] = v;
  __syncthreads();
  if (threadIdx.x == 0) part[blockIdx.x] = ws4[0] + ws4[1] + ws4[2] + ws4[3];
}

__launch_bounds__(256)
__global__ void k_scan_part(int* __restrict__ part, int* __restrict__ row_ptr,
                            int nb, int Nn) {
  __shared__ int sm[256];
  const int t = threadIdx.x;
  int v = (t < nb) ? part[t] : 0;
  sm[t] = v;
  __syncthreads();
  for (int d = 1; d < 256; d <<= 1) {
    int u = (t >= d) ? sm[t - d] : 0;
    __syncthreads();
    sm[t] += u;
    __syncthreads();
  }
  if (t < nb) part[t] = sm[t] - v;
  if (t == 255) row_ptr[Nn] = sm[255];
}

__launch_bounds__(256)
__global__ void k_scan_write(const int* __restrict__ deg, const int* __restrict__ part,
                             int* __restrict__ row_ptr, int* __restrict__ cursor,
                             float* __restrict__ dinv, int Nn) {
  __shared__ int sm[256];
  const int t = threadIdx.x;
  const int i = blockIdx.x * 256 + t;
  int v = (i < Nn) ? deg[i] : 0;
  sm[t] = v;
  __syncthreads();
  for (int d = 1; d < 256; d <<= 1) {
    int u = (t >= d) ? sm[t - d] : 0;
    __syncthreads();
    sm[t] += u;
    __syncthreads();
  }
  if (i < Nn) {
    int pre = part[blockIdx.x] + sm[t] - v;
    row_ptr[i] = pre;
    cursor[i] = pre;
    dinv[i] = rsqrtf((float)v + 1.0f);
  }
}

__global__ void k_csr(const int* __restrict__ src, const int* __restrict__ dst,
                      int* __restrict__ cursor, int* __restrict__ csr_src, int E) {
  int e = blockIdx.x * blockDim.x + threadIdx.x;
  if (e >= E) return;
  int d = dst[e];
  int pos = atomicAdd(&cursor[d], 1);
  csr_src[pos] = src[e];
}

// ---------------- GEMM1: h0 = bf16(x[:, :768]) @ sem_W^T + bias + emb[idx] ----
// A staged directly from f32 x (conversion fused); B (bf16, pre-transposed) via
// global_load_lds. 128x256 tile, 1-D swizzled grid (XCD-paired column tiles).
__launch_bounds__(256, 2)
__global__ void k_gemm1(const float* __restrict__ xf,
                        const u16* __restrict__ B, int ldb,
                        u16* __restrict__ C, int M,
                        const float* __restrict__ bias,
                        const float* __restrict__ emb,
                        const int* __restrict__ idx) {
  __shared__ alignas(16) u16 As[128 * 64];
  __shared__ alignas(16) u16 Bs[256 * 64];
  const int t = threadIdx.x;
  const int l = t & 63;
  const int w = t >> 6;
  const int wro = (w >> 1) * 64;
  const int wco = (w & 1) * 128;
  const int lr = l & 15;
  const int kg = (l >> 4) * 8;
  const int nwg = gridDim.x;
  const int id = blockIdx.x;
  const int q8 = nwg >> 3, r8 = nwg & 7;
  const int xcd = id & 7, rk = id >> 3;
  const int swz = (xcd < r8 ? xcd * (q8 + 1) : r8 * (q8 + 1) + (xcd - r8) * q8) + rk;
  const int brow = (swz >> 1) * 128;
  const int bcol = (swz & 1) * 256;

  // A-staging coords: 8 iters x 16 rows; thread covers 4 consecutive f32 cols
  const int arr = t >> 4;          // row within 16-row group
  const int ac4 = (t & 15) * 4;    // col 0..60

  f32x4 acc[4][8] = {};

  for (int k0 = 0; k0 < BERT_D; k0 += 64) {
    // B first (async DMA overlaps A's VALU staging)
#pragma unroll
    for (int i = 0; i < 8; ++i) {
      const int eo = (i * 256 + t) * 8;
      const int r = eo >> 6;
      const int c = eo & 63;
      gl_lds16(B + (size_t)(bcol + r) * ldb + (k0 + c), Bs + eo);
    }
    // A from f32 x, convert in-register, ds_write_b64
#pragma unroll
    for (int i = 0; i < 8; ++i) {
      const int rr = i * 16 + arr;
      int gr = brow + rr;
      if (gr > M - 1) gr = M - 1;
      const float* xp = xf + (size_t)gr * XSTRIDE + k0 + ac4;
      float f0 = xp[0], f1 = xp[1], f2 = xp[2], f3 = xp[3];
      union { u16 h[4]; unsigned long long q; } pk;
      pk.h[0] = f2us(f0); pk.h[1] = f2us(f1); pk.h[2] = f2us(f2); pk.h[3] = f2us(f3);
      *(unsigned long long*)(As + rr * 64 + ac4) = pk.q;
    }
    __syncthreads();
#pragma unroll
    for (int ks = 0; ks < 2; ++ks) {
      bfv8 af[4], bfr[8];
#pragma unroll
      for (int m = 0; m < 4; ++m)
        af[m] = __builtin_bit_cast(bfv8, *(const uint4*)(As + (wro + m * 16 + lr) * 64 + ks * 32 + kg));
#pragma unroll
      for (int n = 0; n < 8; ++n)
        bfr[n] = __builtin_bit_cast(bfv8, *(const uint4*)(Bs + (wco + n * 16 + lr) * 64 + ks * 32 + kg));
#pragma unroll
      for (int m = 0; m < 4; ++m)
#pragma unroll
        for (int n = 0; n < 8; ++n)
          acc[m][n] = __builtin_amdgcn_mfma_f32_16x16x32_bf16(af[m], bfr[n], acc[m][n], 0, 0, 0);
    }
    __syncthreads();
  }

#pragma unroll
  for (int m = 0; m < 4; ++m) {
#pragma unroll
    for (int r = 0; r < 4; ++r) {
      const int row = brow + wro + m * 16 + (l >> 4) * 4 + r;
      if (row >= M) continue;
#pragma unroll
      for (int n = 0; n < 8; ++n) {
        const int col = bcol + wco + n * 16 + lr;
        float v = acc[m][n][r] + bias[col] + emb[idx[row] * HH + col];
        C[(size_t)row * HH + col] = f2us(v);
      }
    }
  }
}

// ---------------- GEMM (bf16 A): C = A @ B^T, 128x256 tile, 1-D swizzled ------
// EPI=0: plain   EPI=2: row-scale by dscale[row]
template <int EPI>
__launch_bounds__(256, 2)
__global__ void k_gemm_bt(const u16* __restrict__ A, int lda,
                          const u16* __restrict__ B, int ldb,
                          u16* __restrict__ C, int M, int Kd,
                          const float* __restrict__ dscale) {
  __shared__ alignas(16) u16 As[128 * 64];
  __shared__ alignas(16) u16 Bs[256 * 64];
  const int t = threadIdx.x;
  const int l = t & 63;
  const int w = t >> 6;
  const int wro = (w >> 1) * 64;
  const int wco = (w & 1) * 128;
  const int lr = l & 15;
  const int kg = (l >> 4) * 8;
  const int nwg = gridDim.x;
  const int id = blockIdx.x;
  const int q8 = nwg >> 3, r8 = nwg & 7;
  const int xcd = id & 7, rk = id >> 3;
  const int swz = (xcd < r8 ? xcd * (q8 + 1) : r8 * (q8 + 1) + (xcd - r8) * q8) + rk;
  const int brow = (swz >> 1) * 128;
  const int bcol = (swz & 1) * 256;

  f32x4 acc[4][8] = {};

  for (int k0 = 0; k0 < Kd; k0 += 64) {
#pragma unroll
    for (int i = 0; i < 4; ++i) {
      const int eo = (i * 256 + t) * 8;
      const int r = eo >> 6;
      const int c = eo & 63;
      int gr = brow + r;
      if (gr > M - 1) gr = M - 1;
      gl_lds16(A + (size_t)gr * lda + (k0 + c), As + eo);
    }
#pragma unroll
    for (int i = 0; i < 8; ++i) {
      const int eo = (i * 256 + t) * 8;
      const int r = eo >> 6;
      const int c = eo & 63;
      gl_lds16(B + (size_t)(bcol + r) * ldb + (k0 + c), Bs + eo);
    }
    __syncthreads();
#pragma unroll
    for (int ks = 0; ks < 2; ++ks) {
      bfv8 af[4], bfr[8];
#pragma unroll
      for (int m = 0; m < 4; ++m)
        af[m] = __builtin_bit_cast(bfv8, *(const uint4*)(As + (wro + m * 16 + lr) * 64 + ks * 32 + kg));
#pragma unroll
      for (int n = 0; n < 8; ++n)
        bfr[n] = __builtin_bit_cast(bfv8, *(const uint4*)(Bs + (wco + n * 16 + lr) * 64 + ks * 32 + kg));
#pragma unroll
      for (int m = 0; m < 4; ++m)
#pragma unroll
        for (int n = 0; n < 8; ++n)
          acc[m][n] = __builtin_amdgcn_mfma_f32_16x16x32_bf16(af[m], bfr[n], acc[m][n], 0, 0, 0);
    }
    __syncthreads();
  }

#pragma unroll
  for (int m = 0; m < 4; ++m) {
#pragma unroll
    for (int r = 0; r < 4; ++r) {
      const int row = brow + wro + m * 16 + (l >> 4) * 4 + r;
      if (row >= M) continue;
      const float sc = (EPI == 2) ? dscale[row] : 1.0f;
#pragma unroll
      for (int n = 0; n < 8; ++n) {
        const int col = bcol + wco + n * 16 + lr;
        float v = acc[m][n][r];
        if (EPI == 2) v *= sc;
        C[(size_t)row * HH + col] = f2us(v);
      }
    }
  }
}

// ---------------- LayerNorm + GELU (one wave per row) ----------------
__launch_bounds__(256)
__global__ void k_ln_gelu(const u16* __restrict__ h0, const float* __restrict__ gw,
                          const float* __restrict__ bw, u16* __restrict__ hout, int Nn) {
  const int wid = (int)((blockIdx.x * (long long)blockDim.x + threadIdx.x) >> 6);
  if (wid >= Nn) return;
  const int l = threadIdx.x & 63;
  uint4 q = *(const uint4*)(h0 + (size_t)wid * HH + l * 8);
  const u16* us = (const u16*)&q;
  float f[8]; float s = 0.f, s2 = 0.f;
#pragma unroll
  for (int j = 0; j < 8; ++j) { f[j] = us2f(us[j]); s += f[j]; s2 += f[j] * f[j]; }
#pragma unroll
  for (int o = 32; o; o >>= 1) { s += __shfl_xor(s, o); s2 += __shfl_xor(s2, o); }
  const float mean = s * (1.f / 512.f);
  const float var = s2 * (1.f / 512.f) - mean * mean;
  const float rs = rsqrtf(var + 1e-5f);
  union { u16 ov[8]; uint4 q; } o;
#pragma unroll
  for (int j = 0; j < 8; ++j) {
    int col = l * 8 + j;
    float y = (f[j] - mean) * rs * gw[col] + bw[col];
    o.ov[j] = f2us(gelu_f(y));
  }
  *(uint4*)(hout + (size_t)wid * HH + l * 8) = o.q;
}

// ---------------- GCN aggregate (R5 form: 4-deep MLP, self at end) ----------
__launch_bounds__(256)
__global__ void k_agg(const u16* __restrict__ hwS, const int* __restrict__ row_ptr,
                      const int* __restrict__ csr_src, const float* __restrict__ dinv,
                      const float* __restrict__ bias, u16* __restrict__ hout, int Nn) {
  const int wid = (int)((blockIdx.x * (long long)blockDim.x + threadIdx.x) >> 6);
  if (wid >= Nn) return;
  const int l = threadIdx.x & 63;
  const int cb = l * 8;
  float acc[8] = {0.f, 0.f, 0.f, 0.f, 0.f, 0.f, 0.f, 0.f};
  const int lo = row_ptr[wid], hi = row_ptr[wid + 1];
  const float dv = dinv[wid];
  int e = lo;
  for (; e + 4 <= hi; e += 4) {
    const int u0 = csr_src[e + 0];
    const int u1 = csr_src[e + 1];
    const int u2 = csr_src[e + 2];
    const int u3 = csr_src[e + 3];
    uint4 q0 = *(const uint4*)(hwS + (size_t)u0 * HH + cb);
    uint4 q1 = *(const uint4*)(hwS + (size_t)u1 * HH + cb);
    uint4 q2 = *(const uint4*)(hwS + (size_t)u2 * HH + cb);
    uint4 q3 = *(const uint4*)(hwS + (size_t)u3 * HH + cb);
    const u16* p0 = (const u16*)&q0;
    const u16* p1 = (const u16*)&q1;
    const u16* p2 = (const u16*)&q2;
    const u16* p3 = (const u16*)&q3;
#pragma unroll
    for (int j = 0; j < 8; ++j)
      acc[j] += (us2f(p0[j]) + us2f(p1[j])) + (us2f(p2[j]) + us2f(p3[j]));
  }
  for (; e < hi; ++e) {
    const int u = csr_src[e];
    uint4 q = *(const uint4*)(hwS + (size_t)u * HH + cb);
    const u16* p = (const u16*)&q;
#pragma unroll
    for (int j = 0; j < 8; ++j) acc[j] += us2f(p[j]);
  }
  {
    uint4 q = *(const uint4*)(hwS + (size_t)wid * HH + cb);
    const u16* p = (const u16*)&q;
#pragma unroll
    for (int j = 0; j < 8; ++j) acc[j] += us2f(p[j]);
  }
  union { u16 ov[8]; u32x4 q; } o;
#pragma unroll
  for (int j = 0; j < 8; ++j) {
    float v = acc[j] * dv + bias[cb + j];
    o.ov[j] = f2us(gelu_f(v));
  }
  __builtin_nontemporal_store(o.q, (u32x4*)(hout + (size_t)wid * HH + cb));
}

// ---------------- pooling: (G x RS) blocks, NT vector loads, atomic partials ----
#define POOL_RS 16
__launch_bounds__(256)
__global__ void k_pool2(const u16* __restrict__ h1, const u16* __restrict__ h2,
                        const int* __restrict__ batch, float* __restrict__ hg, int Nn) {
  const int g = blockIdx.x;
  const int chunk = blockIdx.y;
  const int t = threadIdx.x;
  const int w = t >> 6;
  const int l = t & 63;
  const int cb = l * 8;
  int lo, hi;
  { int a = 0, b = Nn; while (a < b) { int m = (a + b) >> 1; if (batch[m] < g) a = m + 1; else b = m; } lo = a; }
  { int a = 0, b = Nn; while (a < b) { int m = (a + b) >> 1; if (batch[m] < g + 1) a = m + 1; else b = m; } hi = a; }
  const int len = hi - lo;
  const int per = (len + POOL_RS - 1) / POOL_RS;
  const int rlo = lo + chunk * per;
  const int rhi = min(rlo + per, hi);
  float acc[8] = {};
  for (int r = rlo + w; r < rhi; r += 4) {
    u32x4 a = __builtin_nontemporal_load((const u32x4*)(h1 + (size_t)r * HH + cb));
    u32x4 b = __builtin_nontemporal_load((const u32x4*)(h2 + (size_t)r * HH + cb));
    const u16* ua = (const u16*)&a;
    const u16* ub = (const u16*)&b;
#pragma unroll
    for (int j = 0; j < 8; ++j) acc[j] += us2f(ua[j]) + us2f(ub[j]);
  }
  __shared__ float red[4][HH];
#pragma unroll
  for (int j = 0; j < 8; ++j) red[w][cb + j] = acc[j];
  __syncthreads();
  if (w == 0) {
#pragma unroll
    for (int j = 0; j < 8; ++j) {
      const int col = cb + j;
      float s = red[0][col] + red[1][col] + red[2][col] + red[3][col];
      if (s != 0.f) atomicAdd(&hg[(size_t)g * HH + col], s);
    }
  }
}

// ---------------- classifier (one block per group; divides by count) ---------
__launch_bounds__(256)
__global__ void k_cls(const float* __restrict__ hg, const int* __restrict__ batch,
                      const float* __restrict__ W1, const float* __restrict__ b1,
                      const float* __restrict__ W2, const float* __restrict__ b2,
                      float* __restrict__ out, int Nn) {
  const int g = blockIdx.x;
  const int t = threadIdx.x;
  __shared__ float hl[512];
  __shared__ float zl[512];
  __shared__ float pr[512];
  int lo, hi;
  { int a = 0, b = Nn; while (a < b) { int m = (a + b) >> 1; if (batch[m] < g) a = m + 1; else b = m; } lo = a; }
  { int a = 0, b = Nn; while (a < b) { int m = (a + b) >> 1; if (batch[m] < g + 1) a = m + 1; else b = m; } hi = a; }
  const float inv = 1.0f / fmaxf((float)(hi - lo), 1.0f);
  hl[t] = hg[(size_t)g * HH + t] * inv;
  hl[t + 256] = hg[(size_t)g * HH + t + 256] * inv;
  __syncthreads();
#pragma unroll
  for (int jj = 0; jj < 2; ++jj) {
    const int j = t + jj * 256;
    float a = b1[j];
    for (int k = 0; k < 512; ++k) a += hl[k] * W1[k * HH + j];
    zl[j] = gelu_f(a);
  }
  __syncthreads();
  float p0 = 0.f, p1 = 0.f;
  for (int k = t; k < 512; k += 256) { p0 += zl[k] * W2[k * 2]; p1 += zl[k] * W2[k * 2 + 1]; }
  pr[t] = p0; pr[t + 256] = p1;
  __syncthreads();
  for (int s2 = 128; s2; s2 >>= 1) {
    if (t < s2) { pr[t] += pr[t + s2]; pr[t + 256] += pr[t + 256 + s2]; }
    __syncthreads();
  }
  if (t == 0) { out[g * 2] = pr[0] + b2[0]; out[g * 2 + 1] = pr[256] + b2[1]; }
}

// ---------------- host ----------------
extern "C" void kernel_launch(void* const* d_in, const int* in_sizes, int n_in,
                              void* d_out, int out_size, void* d_ws, size_t ws_size,
                              hipStream_t stream) {
  const float* x        = (const float*)d_in[0];
  const int*   eidx     = (const int*)d_in[1];
  const int*   batch    = (const int*)d_in[2];
  const float* sem_W    = (const float*)d_in[3];
  const float* sem_b    = (const float*)d_in[4];
  const float* sl_emb   = (const float*)d_in[5];
  const float* ln_g     = (const float*)d_in[6];
  const float* ln_b     = (const float*)d_in[7];
  const float* W1       = (const float*)d_in[8];
  const float* b1       = (const float*)d_in[9];
  const float* W2       = (const float*)d_in[10];
  const float* b2       = (const float*)d_in[11];
  const float* cW1      = (const float*)d_in[12];
  const float* cb1      = (const float*)d_in[13];
  const float* cW2      = (const float*)d_in[14];
  const float* cb2      = (const float*)d_in[15];
  const int N_ = in_sizes[2];
  const int E_ = in_sizes[1] / 2;
  const int G_ = out_size / 2;
  const int* src = eidx;
  const int* dst = eidx + E_;

  char* ws = (char*)d_ws;
  size_t off = 0;
  auto alloc = [&](size_t bytes) -> void* {
    void* p = (void*)(ws + off);
    off += (bytes + 255) & ~(size_t)255;
    return p;
  };
  u16* h1 = (u16*)alloc((size_t)N_ * HH * sizeof(u16));
  u16* h0 = (u16*)alloc((size_t)N_ * HH * sizeof(u16));
  u16* hw = h0;                                       // reuse region B
  u16* h = (u16*)alloc((size_t)N_ * HH * sizeof(u16));
  u16* h2 = h;                                        // reuse region C
  u16* semW_T = (u16*)alloc((size_t)HH * BERT_D * sizeof(u16));
  u16* W1T    = (u16*)alloc((size_t)HH * HH * sizeof(u16));
  u16* W2T    = (u16*)alloc((size_t)HH * HH * sizeof(u16));
  int* idx     = (int*)alloc((size_t)N_ * 4);
  int* deg     = (int*)alloc((size_t)N_ * 4);
  float* dinv  = (float*)alloc((size_t)N_ * 4);
  int* row_ptr = (int*)alloc((size_t)(N_ + 1) * 4);
  int* cursor  = (int*)alloc((size_t)N_ * 4);
  int* csr_src = (int*)alloc((size_t)E_ * 4);
  int* part    = (int*)alloc(1024);
  float* hg    = (float*)alloc((size_t)G_ * HH * 4);

  hipMemsetAsync(deg, 0, (size_t)N_ * 4, stream);
  hipMemsetAsync(hg, 0, (size_t)G_ * HH * 4, stream);

  k_idx<<<(N_ + 255) / 256, 256, 0, stream>>>(x, idx, N_);
  k_transpose_bf16<<<(BERT_D * HH + 255) / 256, 256, 0, stream>>>(sem_W, semW_T, BERT_D, HH);
  k_transpose_bf16<<<(HH * HH + 255) / 256, 256, 0, stream>>>(W1, W1T, HH, HH);
  k_transpose_bf16<<<(HH * HH + 255) / 256, 256, 0, stream>>>(W2, W2T, HH, HH);

  const int nb = (N_ + 255) / 256;
  k_deg<<<(E_ + 255) / 256, 256, 0, stream>>>(dst, deg, E_);
  k_part<<<nb, 256, 0, stream>>>(deg, part, N_);
  k_scan_part<<<1, 256, 0, stream>>>(part, row_ptr, nb, N_);
  k_scan_write<<<nb, 256, 0, stream>>>(deg, part, row_ptr, cursor, dinv, N_);
  k_csr<<<(E_ + 255) / 256, 256, 0, stream>>>(src, dst, cursor, csr_src, E_);

  const int Mtiles = (N_ + 127) / 128;
  const int wave_blocks = (N_ + 3) / 4;
  const int gemm_grid = Mtiles * 2;   // 1-D, swizzled in-kernel

  // h0 = bf16(x) @ sem_W + sem_b + slice_emb[idx]   (conversion fused)
  k_gemm1<<<gemm_grid, 256, 0, stream>>>(
      x, semW_T, BERT_D, h0, N_, sem_b, sl_emb, idx);
  // h = gelu(LN(h0))
  k_ln_gelu<<<wave_blocks, 256, 0, stream>>>(h0, ln_g, ln_b, h, N_);
  // conv1: hwS = (h @ W1) * dinv[row] ; h1 = gelu((agg+self)*dinv + b1)
  k_gemm_bt<2><<<gemm_grid, 256, 0, stream>>>(
      h, HH, W1T, HH, hw, N_, HH, dinv);
  k_agg<<<wave_blocks, 256, 0, stream>>>(hw, row_ptr, csr_src, dinv, b1, h1, N_);
  // conv2: hwS = (h1 @ W2) * dinv[row] ; h2 = gelu((agg+self)*dinv + b2)
  k_gemm_bt<2><<<gemm_grid, 256, 0, stream>>>(
      h1, HH, W2T, HH, hw, N_, HH, dinv);
  k_agg<<<wave_blocks, 256, 0, stream>>>(hw, row_ptr, csr_src, dinv, b2, h2, N_);
  // pool (h1 + h2 residual fused) + classifier
  k_pool2<<<dim3(G_, POOL_RS), 256, 0, stream>>>(h1, h2, batch, hg, N_);
  k_cls<<<G_, 256, 0, stream>>>(hg, batch, cW1, cb1, cW2, cb2, (float*)d_out, N_);
}

// Round 8
// 701.242 us; speedup vs baseline: 1.0673x; 1.0343x over previous
//
#include <hip/hip_runtime.h>
#include <hip/hip_bf16.h>

typedef unsigned short u16;
typedef __bf16 bfv8 __attribute__((ext_vector_type(8)));
typedef float f32x4 __attribute__((ext_vector_type(4)));
typedef unsigned int u32x4 __attribute__((ext_vector_type(4)));

#define HH 512
#define BERT_D 768
#define XSTRIDE 769

__device__ __forceinline__ float gelu_f(float x) {
  return 0.5f * x * (1.0f + erff(x * 0.70710678118654752440f));
}
__device__ __forceinline__ float us2f(u16 u) {
  union { unsigned int i; float f; } c; c.i = ((unsigned int)u) << 16; return c.f;
}
__device__ __forceinline__ u16 f2us(float f) {
  union { float f; unsigned int i; } c; c.f = f;
  unsigned int i = c.i;
  i += 0x7FFFu + ((i >> 16) & 1u);
  return (u16)(i >> 16);
}
__device__ __forceinline__ void gl_lds16(const u16* g, u16* l) {
  __builtin_amdgcn_global_load_lds((const __attribute__((address_space(1))) void*)g,
                                   (__attribute__((address_space(3))) void*)l, 16, 0, 0);
}

// ---------------- idx extraction ----------------
__global__ void k_idx(const float* __restrict__ x, int* __restrict__ idx, int Nn) {
  int i = blockIdx.x * blockDim.x + threadIdx.x;
  if (i < Nn) idx[i] = (int)x[(size_t)i * XSTRIDE + BERT_D];
}

__global__ void k_transpose_bf16(const float* __restrict__ src, u16* __restrict__ dst,
                                 int K, int Nn) {
  int i = blockIdx.x * blockDim.x + threadIdx.x;
  if (i >= K * Nn) return;
  int k = i / Nn, j = i - k * Nn;
  dst[(size_t)j * K + k] = f2us(src[i]);
}

// ---------------- graph prep ----------------
__global__ void k_deg(const int* __restrict__ dst, int* __restrict__ deg, int E) {
  int e = blockIdx.x * blockDim.x + threadIdx.x;
  if (e < E) atomicAdd(&deg[dst[e]], 1);
}

__launch_bounds__(256)
__global__ void k_part(const int* __restrict__ deg, int* __restrict__ part, int Nn) {
  const int i = blockIdx.x * 256 + threadIdx.x;
  int v = (i < Nn) ? deg[i] : 0;
#pragma unroll
  for (int o = 32; o; o >>= 1) v += __shfl_xor(v, o);
  __shared__ int ws4[4];
  if ((threadIdx.x & 63) == 0) ws4[threadIdx.x >> 6] = v;
  __syncthreads();
  if (threadIdx.x == 0) part[blockIdx.x] = ws4[0] + ws4[1] + ws4[2] + ws4[3];
}

__launch_bounds__(256)
__global__ void k_scan_part(int* __restrict__ part, int* __restrict__ row_ptr,
                            int nb, int Nn) {
  __shared__ int sm[256];
  const int t = threadIdx.x;
  int v = (t < nb) ? part[t] : 0;
  sm[t] = v;
  __syncthreads();
  for (int d = 1; d < 256; d <<= 1) {
    int u = (t >= d) ? sm[t - d] : 0;
    __syncthreads();
    sm[t] += u;
    __syncthreads();
  }
  if (t < nb) part[t] = sm[t] - v;
  if (t == 255) row_ptr[Nn] = sm[255];
}

__launch_bounds__(256)
__global__ void k_scan_write(const int* __restrict__ deg, const int* __restrict__ part,
                             int* __restrict__ row_ptr, int* __restrict__ cursor,
                             float* __restrict__ dinv, int Nn) {
  __shared__ int sm[256];
  const int t = threadIdx.x;
  const int i = blockIdx.x * 256 + t;
  int v = (i < Nn) ? deg[i] : 0;
  sm[t] = v;
  __syncthreads();
  for (int d = 1; d < 256; d <<= 1) {
    int u = (t >= d) ? sm[t - d] : 0;
    __syncthreads();
    sm[t] += u;
    __syncthreads();
  }
  if (i < Nn) {
    int pre = part[blockIdx.x] + sm[t] - v;
    row_ptr[i] = pre;
    cursor[i] = pre;
    dinv[i] = rsqrtf((float)v + 1.0f);
  }
}

__global__ void k_csr(const int* __restrict__ src, const int* __restrict__ dst,
                      int* __restrict__ cursor, int* __restrict__ csr_src, int E) {
  int e = blockIdx.x * blockDim.x + threadIdx.x;
  if (e >= E) return;
  int d = dst[e];
  int pos = atomicAdd(&cursor[d], 1);
  csr_src[pos] = src[e];
}

// ================= GEMM kernels, T2 XOR-swizzled LDS =================
// Invariant: LDS[row][g16] = global[row][g16 ^ (row&7)]  (g16 = 16B granule 0..7)
//  - gl_lds staging: LDS linear (base+lane*16), SOURCE col granule = (t&7)^((t>>3)&7)
//  - ds_read: granule (ks*4+kq) ^ (lr&7)   [row&7 == lr&7: subtile offsets %16==0]

// ---------------- GEMM1: h0 = bf16(x[:, :768]) @ sem_W^T + bias + emb[idx] ----
__launch_bounds__(256, 2)
__global__ void k_gemm1(const float* __restrict__ xf,
                        const u16* __restrict__ B, int ldb,
                        u16* __restrict__ C, int M,
                        const float* __restrict__ bias,
                        const float* __restrict__ emb,
                        const int* __restrict__ idx) {
  __shared__ alignas(16) u16 As[128 * 64];
  __shared__ alignas(16) u16 Bs[256 * 64];
  const int t = threadIdx.x;
  const int l = t & 63;
  const int w = t >> 6;
  const int wro = (w >> 1) * 64;
  const int wco = (w & 1) * 128;
  const int lr = l & 15;
  const int kq = l >> 4;            // 0..3
  const int rsw = lr & 7;           // read-side XOR
  const int nwg = gridDim.x;
  const int id = blockIdx.x;
  const int q8 = nwg >> 3, r8 = nwg & 7;
  const int xcd = id & 7, rk = id >> 3;
  const int swz = (xcd < r8 ? xcd * (q8 + 1) : r8 * (q8 + 1) + (xcd - r8) * q8) + rk;
  const int brow = (swz >> 1) * 128;
  const int bcol = (swz & 1) * 256;

  // B staging: pre-swizzled source col
  const int bsw8 = (((t & 7) ^ ((t >> 3) & 7)) * 8);
  // A staging coords (f32 source, ds_write dest swizzled)
  const int arr = t >> 4;           // row within 16-row group
  const int ac4 = (t & 15) * 4;     // linear f32 col
  const int asub = (t & 1) * 4;     // element sub-offset within granule
  const int aswz = (((t & 15) >> 1) ^ (arr & 7)) * 8;  // dest granule (elems)

  f32x4 acc[4][8] = {};

  for (int k0 = 0; k0 < BERT_D; k0 += 64) {
#pragma unroll
    for (int i = 0; i < 8; ++i) {
      const int eo = (i * 256 + t) * 8;
      const int r = eo >> 6;
      gl_lds16(B + (size_t)(bcol + r) * ldb + (k0 + bsw8), Bs + eo);
    }
#pragma unroll
    for (int i = 0; i < 8; ++i) {
      const int rr = i * 16 + arr;
      int gr = brow + rr;
      if (gr > M - 1) gr = M - 1;
      const float* xp = xf + (size_t)gr * XSTRIDE + k0 + ac4;
      float f0 = xp[0], f1 = xp[1], f2 = xp[2], f3 = xp[3];
      union { u16 h[4]; unsigned long long q; } pk;
      pk.h[0] = f2us(f0); pk.h[1] = f2us(f1); pk.h[2] = f2us(f2); pk.h[3] = f2us(f3);
      *(unsigned long long*)(As + rr * 64 + aswz + asub) = pk.q;
    }
    __syncthreads();
#pragma unroll
    for (int ks = 0; ks < 2; ++ks) {
      bfv8 af[4], bfr[8];
      const int rg = ((ks * 4 + kq) ^ rsw) * 8;
#pragma unroll
      for (int m = 0; m < 4; ++m)
        af[m] = __builtin_bit_cast(bfv8, *(const uint4*)(As + (wro + m * 16 + lr) * 64 + rg));
#pragma unroll
      for (int n = 0; n < 8; ++n)
        bfr[n] = __builtin_bit_cast(bfv8, *(const uint4*)(Bs + (wco + n * 16 + lr) * 64 + rg));
#pragma unroll
      for (int m = 0; m < 4; ++m)
#pragma unroll
        for (int n = 0; n < 8; ++n)
          acc[m][n] = __builtin_amdgcn_mfma_f32_16x16x32_bf16(af[m], bfr[n], acc[m][n], 0, 0, 0);
    }
    __syncthreads();
  }

#pragma unroll
  for (int m = 0; m < 4; ++m) {
#pragma unroll
    for (int r = 0; r < 4; ++r) {
      const int row = brow + wro + m * 16 + (l >> 4) * 4 + r;
      if (row >= M) continue;
#pragma unroll
      for (int n = 0; n < 8; ++n) {
        const int col = bcol + wco + n * 16 + lr;
        float v = acc[m][n][r] + bias[col] + emb[idx[row] * HH + col];
        C[(size_t)row * HH + col] = f2us(v);
      }
    }
  }
}

// ---------------- GEMM (bf16 A): C = A @ B^T, 128x256 tile, swizzled ---------
// EPI=0: plain   EPI=2: row-scale by dscale[row]
template <int EPI>
__launch_bounds__(256, 2)
__global__ void k_gemm_bt(const u16* __restrict__ A, int lda,
                          const u16* __restrict__ B, int ldb,
                          u16* __restrict__ C, int M, int Kd,
                          const float* __restrict__ dscale) {
  __shared__ alignas(16) u16 As[128 * 64];
  __shared__ alignas(16) u16 Bs[256 * 64];
  const int t = threadIdx.x;
  const int l = t & 63;
  const int w = t >> 6;
  const int wro = (w >> 1) * 64;
  const int wco = (w & 1) * 128;
  const int lr = l & 15;
  const int kq = l >> 4;
  const int rsw = lr & 7;
  const int nwg = gridDim.x;
  const int id = blockIdx.x;
  const int q8 = nwg >> 3, r8 = nwg & 7;
  const int xcd = id & 7, rk = id >> 3;
  const int swz = (xcd < r8 ? xcd * (q8 + 1) : r8 * (q8 + 1) + (xcd - r8) * q8) + rk;
  const int brow = (swz >> 1) * 128;
  const int bcol = (swz & 1) * 256;

  const int ssw8 = (((t & 7) ^ ((t >> 3) & 7)) * 8);  // staging source col (elems)

  f32x4 acc[4][8] = {};

  for (int k0 = 0; k0 < Kd; k0 += 64) {
#pragma unroll
    for (int i = 0; i < 4; ++i) {
      const int eo = (i * 256 + t) * 8;
      const int r = eo >> 6;
      int gr = brow + r;
      if (gr > M - 1) gr = M - 1;
      gl_lds16(A + (size_t)gr * lda + (k0 + ssw8), As + eo);
    }
#pragma unroll
    for (int i = 0; i < 8; ++i) {
      const int eo = (i * 256 + t) * 8;
      const int r = eo >> 6;
      gl_lds16(B + (size_t)(bcol + r) * ldb + (k0 + ssw8), Bs + eo);
    }
    __syncthreads();
#pragma unroll
    for (int ks = 0; ks < 2; ++ks) {
      bfv8 af[4], bfr[8];
      const int rg = ((ks * 4 + kq) ^ rsw) * 8;
#pragma unroll
      for (int m = 0; m < 4; ++m)
        af[m] = __builtin_bit_cast(bfv8, *(const uint4*)(As + (wro + m * 16 + lr) * 64 + rg));
#pragma unroll
      for (int n = 0; n < 8; ++n)
        bfr[n] = __builtin_bit_cast(bfv8, *(const uint4*)(Bs + (wco + n * 16 + lr) * 64 + rg));
#pragma unroll
      for (int m = 0; m < 4; ++m)
#pragma unroll
        for (int n = 0; n < 8; ++n)
          acc[m][n] = __builtin_amdgcn_mfma_f32_16x16x32_bf16(af[m], bfr[n], acc[m][n], 0, 0, 0);
    }
    __syncthreads();
  }

#pragma unroll
  for (int m = 0; m < 4; ++m) {
#pragma unroll
    for (int r = 0; r < 4; ++r) {
      const int row = brow + wro + m * 16 + (l >> 4) * 4 + r;
      if (row >= M) continue;
      const float sc = (EPI == 2) ? dscale[row] : 1.0f;
#pragma unroll
      for (int n = 0; n < 8; ++n) {
        const int col = bcol + wco + n * 16 + lr;
        float v = acc[m][n][r];
        if (EPI == 2) v *= sc;
        C[(size_t)row * HH + col] = f2us(v);
      }
    }
  }
}

// ---------------- LayerNorm + GELU (one wave per row) ----------------
__launch_bounds__(256)
__global__ void k_ln_gelu(const u16* __restrict__ h0, const float* __restrict__ gw,
                          const float* __restrict__ bw, u16* __restrict__ hout, int Nn) {
  const int wid = (int)((blockIdx.x * (long long)blockDim.x + threadIdx.x) >> 6);
  if (wid >= Nn) return;
  const int l = threadIdx.x & 63;
  uint4 q = *(const uint4*)(h0 + (size_t)wid * HH + l * 8);
  const u16* us = (const u16*)&q;
  float f[8]; float s = 0.f, s2 = 0.f;
#pragma unroll
  for (int j = 0; j < 8; ++j) { f[j] = us2f(us[j]); s += f[j]; s2 += f[j] * f[j]; }
#pragma unroll
  for (int o = 32; o; o >>= 1) { s += __shfl_xor(s, o); s2 += __shfl_xor(s2, o); }
  const float mean = s * (1.f / 512.f);
  const float var = s2 * (1.f / 512.f) - mean * mean;
  const float rs = rsqrtf(var + 1e-5f);
  union { u16 ov[8]; uint4 q; } o;
#pragma unroll
  for (int j = 0; j < 8; ++j) {
    int col = l * 8 + j;
    float y = (f[j] - mean) * rs * gw[col] + bw[col];
    o.ov[j] = f2us(gelu_f(y));
  }
  *(uint4*)(hout + (size_t)wid * HH + l * 8) = o.q;
}

// ---------------- GCN aggregate (R5 form: 4-deep MLP, self at end) ----------
__launch_bounds__(256)
__global__ void k_agg(const u16* __restrict__ hwS, const int* __restrict__ row_ptr,
                      const int* __restrict__ csr_src, const float* __restrict__ dinv,
                      const float* __restrict__ bias, u16* __restrict__ hout, int Nn) {
  const int wid = (int)((blockIdx.x * (long long)blockDim.x + threadIdx.x) >> 6);
  if (wid >= Nn) return;
  const int l = threadIdx.x & 63;
  const int cb = l * 8;
  float acc[8] = {0.f, 0.f, 0.f, 0.f, 0.f, 0.f, 0.f, 0.f};
  const int lo = row_ptr[wid], hi = row_ptr[wid + 1];
  const float dv = dinv[wid];
  int e = lo;
  for (; e + 4 <= hi; e += 4) {
    const int u0 = csr_src[e + 0];
    const int u1 = csr_src[e + 1];
    const int u2 = csr_src[e + 2];
    const int u3 = csr_src[e + 3];
    uint4 q0 = *(const uint4*)(hwS + (size_t)u0 * HH + cb);
    uint4 q1 = *(const uint4*)(hwS + (size_t)u1 * HH + cb);
    uint4 q2 = *(const uint4*)(hwS + (size_t)u2 * HH + cb);
    uint4 q3 = *(const uint4*)(hwS + (size_t)u3 * HH + cb);
    const u16* p0 = (const u16*)&q0;
    const u16* p1 = (const u16*)&q1;
    const u16* p2 = (const u16*)&q2;
    const u16* p3 = (const u16*)&q3;
#pragma unroll
    for (int j = 0; j < 8; ++j)
      acc[j] += (us2f(p0[j]) + us2f(p1[j])) + (us2f(p2[j]) + us2f(p3[j]));
  }
  for (; e < hi; ++e) {
    const int u = csr_src[e];
    uint4 q = *(const uint4*)(hwS + (size_t)u * HH + cb);
    const u16* p = (const u16*)&q;
#pragma unroll
    for (int j = 0; j < 8; ++j) acc[j] += us2f(p[j]);
  }
  {
    uint4 q = *(const uint4*)(hwS + (size_t)wid * HH + cb);
    const u16* p = (const u16*)&q;
#pragma unroll
    for (int j = 0; j < 8; ++j) acc[j] += us2f(p[j]);
  }
  union { u16 ov[8]; u32x4 q; } o;
#pragma unroll
  for (int j = 0; j < 8; ++j) {
    float v = acc[j] * dv + bias[cb + j];
    o.ov[j] = f2us(gelu_f(v));
  }
  __builtin_nontemporal_store(o.q, (u32x4*)(hout + (size_t)wid * HH + cb));
}

// ---------------- pooling: (G x RS) blocks, NT vector loads, atomic partials ----
#define POOL_RS 16
__launch_bounds__(256)
__global__ void k_pool2(const u16* __restrict__ h1, const u16* __restrict__ h2,
                        const int* __restrict__ batch, float* __restrict__ hg, int Nn) {
  const int g = blockIdx.x;
  const int chunk = blockIdx.y;
  const int t = threadIdx.x;
  const int w = t >> 6;
  const int l = t & 63;
  const int cb = l * 8;
  int lo, hi;
  { int a = 0, b = Nn; while (a < b) { int m = (a + b) >> 1; if (batch[m] < g) a = m + 1; else b = m; } lo = a; }
  { int a = 0, b = Nn; while (a < b) { int m = (a + b) >> 1; if (batch[m] < g + 1) a = m + 1; else b = m; } hi = a; }
  const int len = hi - lo;
  const int per = (len + POOL_RS - 1) / POOL_RS;
  const int rlo = lo + chunk * per;
  const int rhi = min(rlo + per, hi);
  float acc[8] = {};
  for (int r = rlo + w; r < rhi; r += 4) {
    u32x4 a = __builtin_nontemporal_load((const u32x4*)(h1 + (size_t)r * HH + cb));
    u32x4 b = __builtin_nontemporal_load((const u32x4*)(h2 + (size_t)r * HH + cb));
    const u16* ua = (const u16*)&a;
    const u16* ub = (const u16*)&b;
#pragma unroll
    for (int j = 0; j < 8; ++j) acc[j] += us2f(ua[j]) + us2f(ub[j]);
  }
  __shared__ float red[4][HH];
#pragma unroll
  for (int j = 0; j < 8; ++j) red[w][cb + j] = acc[j];
  __syncthreads();
  if (w == 0) {
#pragma unroll
    for (int j = 0; j < 8; ++j) {
      const int col = cb + j;
      float s = red[0][col] + red[1][col] + red[2][col] + red[3][col];
      if (s != 0.f) atomicAdd(&hg[(size_t)g * HH + col], s);
    }
  }
}

// ---------------- classifier (one block per group; divides by count) ---------
__launch_bounds__(256)
__global__ void k_cls(const float* __restrict__ hg, const int* __restrict__ batch,
                      const float* __restrict__ W1, const float* __restrict__ b1,
                      const float* __restrict__ W2, const float* __restrict__ b2,
                      float* __restrict__ out, int Nn) {
  const int g = blockIdx.x;
  const int t = threadIdx.x;
  __shared__ float hl[512];
  __shared__ float zl[512];
  __shared__ float pr[512];
  int lo, hi;
  { int a = 0, b = Nn; while (a < b) { int m = (a + b) >> 1; if (batch[m] < g) a = m + 1; else b = m; } lo = a; }
  { int a = 0, b = Nn; while (a < b) { int m = (a + b) >> 1; if (batch[m] < g + 1) a = m + 1; else b = m; } hi = a; }
  const float inv = 1.0f / fmaxf((float)(hi - lo), 1.0f);
  hl[t] = hg[(size_t)g * HH + t] * inv;
  hl[t + 256] = hg[(size_t)g * HH + t + 256] * inv;
  __syncthreads();
#pragma unroll
  for (int jj = 0; jj < 2; ++jj) {
    const int j = t + jj * 256;
    float a = b1[j];
    for (int k = 0; k < 512; ++k) a += hl[k] * W1[k * HH + j];
    zl[j] = gelu_f(a);
  }
  __syncthreads();
  float p0 = 0.f, p1 = 0.f;
  for (int k = t; k < 512; k += 256) { p0 += zl[k] * W2[k * 2]; p1 += zl[k] * W2[k * 2 + 1]; }
  pr[t] = p0; pr[t + 256] = p1;
  __syncthreads();
  for (int s2 = 128; s2; s2 >>= 1) {
    if (t < s2) { pr[t] += pr[t + s2]; pr[t + 256] += pr[t + 256 + s2]; }
    __syncthreads();
  }
  if (t == 0) { out[g * 2] = pr[0] + b2[0]; out[g * 2 + 1] = pr[256] + b2[1]; }
}

// ---------------- host ----------------
extern "C" void kernel_launch(void* const* d_in, const int* in_sizes, int n_in,
                              void* d_out, int out_size, void* d_ws, size_t ws_size,
                              hipStream_t stream) {
  const float* x        = (const float*)d_in[0];
  const int*   eidx     = (const int*)d_in[1];
  const int*   batch    = (const int*)d_in[2];
  const float* sem_W    = (const float*)d_in[3];
  const float* sem_b    = (const float*)d_in[4];
  const float* sl_emb   = (const float*)d_in[5];
  const float* ln_g     = (const float*)d_in[6];
  const float* ln_b     = (const float*)d_in[7];
  const float* W1       = (const float*)d_in[8];
  const float* b1       = (const float*)d_in[9];
  const float* W2       = (const float*)d_in[10];
  const float* b2       = (const float*)d_in[11];
  const float* cW1      = (const float*)d_in[12];
  const float* cb1      = (const float*)d_in[13];
  const float* cW2      = (const float*)d_in[14];
  const float* cb2      = (const float*)d_in[15];
  const int N_ = in_sizes[2];
  const int E_ = in_sizes[1] / 2;
  const int G_ = out_size / 2;
  const int* src = eidx;
  const int* dst = eidx + E_;

  char* ws = (char*)d_ws;
  size_t off = 0;
  auto alloc = [&](size_t bytes) -> void* {
    void* p = (void*)(ws + off);
    off += (bytes + 255) & ~(size_t)255;
    return p;
  };
  u16* h1 = (u16*)alloc((size_t)N_ * HH * sizeof(u16));
  u16* h0 = (u16*)alloc((size_t)N_ * HH * sizeof(u16));
  u16* hw = h0;                                       // reuse region B
  u16* h = (u16*)alloc((size_t)N_ * HH * sizeof(u16));
  u16* h2 = h;                                        // reuse region C
  u16* semW_T = (u16*)alloc((size_t)HH * BERT_D * sizeof(u16));
  u16* W1T    = (u16*)alloc((size_t)HH * HH * sizeof(u16));
  u16* W2T    = (u16*)alloc((size_t)HH * HH * sizeof(u16));
  int* idx     = (int*)alloc((size_t)N_ * 4);
  int* deg     = (int*)alloc((size_t)N_ * 4);
  float* dinv  = (float*)alloc((size_t)N_ * 4);
  int* row_ptr = (int*)alloc((size_t)(N_ + 1) * 4);
  int* cursor  = (int*)alloc((size_t)N_ * 4);
  int* csr_src = (int*)alloc((size_t)E_ * 4);
  int* part    = (int*)alloc(1024);
  float* hg    = (float*)alloc((size_t)G_ * HH * 4);

  hipMemsetAsync(deg, 0, (size_t)N_ * 4, stream);
  hipMemsetAsync(hg, 0, (size_t)G_ * HH * 4, stream);

  k_idx<<<(N_ + 255) / 256, 256, 0, stream>>>(x, idx, N_);
  k_transpose_bf16<<<(BERT_D * HH + 255) / 256, 256, 0, stream>>>(sem_W, semW_T, BERT_D, HH);
  k_transpose_bf16<<<(HH * HH + 255) / 256, 256, 0, stream>>>(W1, W1T, HH, HH);
  k_transpose_bf16<<<(HH * HH + 255) / 256, 256, 0, stream>>>(W2, W2T, HH, HH);

  const int nb = (N_ + 255) / 256;
  k_deg<<<(E_ + 255) / 256, 256, 0, stream>>>(dst, deg, E_);
  k_part<<<nb, 256, 0, stream>>>(deg, part, N_);
  k_scan_part<<<1, 256, 0, stream>>>(part, row_ptr, nb, N_);
  k_scan_write<<<nb, 256, 0, stream>>>(deg, part, row_ptr, cursor, dinv, N_);
  k_csr<<<(E_ + 255) / 256, 256, 0, stream>>>(src, dst, cursor, csr_src, E_);

  const int Mtiles = (N_ + 127) / 128;
  const int wave_blocks = (N_ + 3) / 4;
  const int gemm_grid = Mtiles * 2;   // 1-D, swizzled in-kernel

  // h0 = bf16(x) @ sem_W + sem_b + slice_emb[idx]   (conversion fused)
  k_gemm1<<<gemm_grid, 256, 0, stream>>>(
      x, semW_T, BERT_D, h0, N_, sem_b, sl_emb, idx);
  // h = gelu(LN(h0))
  k_ln_gelu<<<wave_blocks, 256, 0, stream>>>(h0, ln_g, ln_b, h, N_);
  // conv1: hwS = (h @ W1) * dinv[row] ; h1 = gelu((agg+self)*dinv + b1)
  k_gemm_bt<2><<<gemm_grid, 256, 0, stream>>>(
      h, HH, W1T, HH, hw, N_, HH, dinv);
  k_agg<<<wave_blocks, 256, 0, stream>>>(hw, row_ptr, csr_src, dinv, b1, h1, N_);
  // conv2: hwS = (h1 @ W2) * dinv[row] ; h2 = gelu((agg+self)*dinv + b2)
  k_gemm_bt<2><<<gemm_grid, 256, 0, stream>>>(
      h1, HH, W2T, HH, hw, N_, HH, dinv);
  k_agg<<<wave_blocks, 256, 0, stream>>>(hw, row_ptr, csr_src, dinv, b2, h2, N_);
  // pool (h1 + h2 residual fused) + classifier
  k_pool2<<<dim3(G_, POOL_RS), 256, 0, stream>>>(h1, h2, batch, hg, N_);
  k_cls<<<G_, 256, 0, stream>>>(hg, batch, cW1, cb1, cW2, cb2, (float*)d_out, N_);
}